// Round 10
// baseline (24.711 us; speedup 1.0000x reference)
//
#include <hip/hip_runtime.h>

#define NN   640
#define NW   20    // used bitmask words per node
#define NWP  24    // padded row stride (96 B -> every row 16B-aligned)
#define H    64
#define MAXD 96    // degree cap; deg ~ Binomial(1279,.0187), mean 23.9

// ---------------- K1: prep (scatter version — no per-block edge scan) ----------------
// blocks 0..319 : waves 0-3: xa = x@W1a, xc = x@W0a for nodes {2b, 2b+1};
//                 waves 4-7: edge scatter (1 edge/thread, global atomicOr into
//                 pre-zeroed bits; only blocks 0..~59 carry edges).
// blocks 320..327: Wf = W1b @ W0a (8 rows/block, one row per wave)
// block  328     : bf = b1b @ W0a
__global__ __launch_bounds__(512) void prep(
    const int* __restrict__ ei, int E,
    const float* __restrict__ x,
    const float* __restrict__ W1a, const float* __restrict__ W0a,
    const float* __restrict__ W1b, const float* __restrict__ b1b,
    unsigned* __restrict__ bits, float* __restrict__ xa, float* __restrict__ xc,
    float* __restrict__ Wf, float* __restrict__ bf)
{
    const int t = threadIdx.x, lane = t & 63, wave = t >> 6, bid = blockIdx.x;

    if (bid < 320) {
        if (wave < 4) {                       // waves 0,1: xa; waves 2,3: xc
            const int v = bid * 2 + (wave & 1);
            const float* W = (wave < 2) ? W1a : W0a;
            const float xv = x[v * H + lane];
            float a0 = 0, a1 = 0, a2 = 0, a3 = 0;
            #pragma unroll
            for (int k = 0; k < H; k += 4) {
                a0 += __shfl(xv, k, 64)     * W[k * H + lane];
                a1 += __shfl(xv, k + 1, 64) * W[(k + 1) * H + lane];
                a2 += __shfl(xv, k + 2, 64) * W[(k + 2) * H + lane];
                a3 += __shfl(xv, k + 3, 64) * W[(k + 3) * H + lane];
            }
            float r = (a0 + a1) + (a2 + a3);
            if (wave < 2) xa[v * H + lane] = r; else xc[v * H + lane] = r;
        } else {                              // waves 4-7: edge scatter
            const int g = bid * 256 + (t - 256);
            if (g < E) {
                int a = ei[g], b = ei[g + E];
                if (a != b) atomicOr(&bits[a * NWP + (b >> 5)], 1u << (b & 31));
            }
        }
    } else if (bid < 328) {
        const int d = (bid - 320) * 8 + wave;
        const float wv = W1b[d * 65 + lane];          // lane e holds W1b[d][e]
        float a0 = 0, a1 = 0, a2 = 0, a3 = 0;
        #pragma unroll
        for (int e = 0; e < 64; e += 4) {
            a0 += __shfl(wv, e, 64)     * W0a[e * H + lane];
            a1 += __shfl(wv, e + 1, 64) * W0a[(e + 1) * H + lane];
            a2 += __shfl(wv, e + 2, 64) * W0a[(e + 2) * H + lane];
            a3 += __shfl(wv, e + 3, 64) * W0a[(e + 3) * H + lane];
        }
        Wf[d * H + lane] = (a0 + a1) + (a2 + a3) + W1b[d * 65 + 64] * W0a[64 * H + lane];
    } else if (wave == 0) {
        const float bv = b1b[lane];
        float a0 = 0, a1 = 0, a2 = 0, a3 = 0;
        #pragma unroll
        for (int e = 0; e < 64; e += 4) {
            a0 += __shfl(bv, e, 64)     * W0a[e * H + lane];
            a1 += __shfl(bv, e + 1, 64) * W0a[(e + 1) * H + lane];
            a2 += __shfl(bv, e + 2, 64) * W0a[(e + 2) * H + lane];
            a3 += __shfl(bv, e + 3, 64) * W0a[(e + 3) * H + lane];
        }
        bf[lane] = (a0 + a1) + (a2 + a3) + b1b[64] * W0a[64 * H + lane];
    }
}

// ---------------- K2: fused per-node ego computation (round-9 verbatim) ----------------
__global__ __launch_bounds__(512, 6) void fused(
    const float* __restrict__ xa,  const float* __restrict__ xc,
    const float* __restrict__ W1a, const float* __restrict__ b1a,
    const float* __restrict__ Wf,  const float* __restrict__ bf,
    const float* __restrict__ b0a,
    const float* __restrict__ W0b, const float* __restrict__ b0b,
    const unsigned* __restrict__ bits,
    float* __restrict__ out)
{
    __shared__ __align__(16) unsigned rowv[NW];
    __shared__ float xr[MAXD][H];                 // xa rows of N(v)
    __shared__ float p1[8][H];
    __shared__ float p2[8][H];
    __shared__ unsigned short ulist[MAXD];
    __shared__ int pre[NW];
    __shared__ int s_deg;

    const int v = blockIdx.x, t = threadIdx.x;
    const int lane = t & 63, wave = t >> 6;

    if (t < NW) rowv[t] = bits[v * NWP + t];
    __syncthreads();

    // enumeration: shfl-scan prefix popcount over the 20 words
    if (wave == 0) {
        unsigned word = (lane < NW) ? rowv[lane] : 0u;
        int pc = __popc(word), scan = pc;
        #pragma unroll
        for (int off = 1; off < 32; off <<= 1) {
            int nb = __shfl_up(scan, off, 64);
            if (lane >= off) scan += nb;
        }
        int o = scan - pc;                        // exclusive prefix
        if (lane < NW) pre[lane] = o;
        unsigned c = word;
        while (c) {
            int b = __ffs(c) - 1; c &= c - 1;
            if (o < MAXD) ulist[o] = (unsigned short)(lane * 32 + b);
            ++o;
        }
        if (lane == NW - 1) s_deg = (o < MAXD) ? o : MAXD;
    }
    __syncthreads();
    const int deg = s_deg;

    // stage xa rows of N(v) into LDS (one coalesced latency round)
    for (int p = wave; p < deg; p += 8)
        xr[p][lane] = xa[ulist[p] * H + lane];

    const float r64 = W1a[64 * H + lane];
    const float k0  = b1a[lane] + r64;            // b1a + 1*W1a[64]
    const float k1  = r64 + W1a[65 * H + lane];   // per-cnt term

    unsigned rw[NW];
    #pragma unroll
    for (int j = 0; j < NW; ++j) rw[j] = rowv[j];
    __syncthreads();

    float hacc = 0.f;
    for (int p = wave; p < deg; p += 8) {
        const uint4* bu = (const uint4*)(bits + ulist[p] * NWP);  // 16B-aligned
        const uint4 q0 = bu[0], q1 = bu[1], q2 = bu[2], q3 = bu[3], q4 = bu[4];
        unsigned cw[NW] = {
            rw[0]  & q0.x, rw[1]  & q0.y, rw[2]  & q0.z, rw[3]  & q0.w,
            rw[4]  & q1.x, rw[5]  & q1.y, rw[6]  & q1.z, rw[7]  & q1.w,
            rw[8]  & q2.x, rw[9]  & q2.y, rw[10] & q2.z, rw[11] & q2.w,
            rw[12] & q3.x, rw[13] & q3.y, rw[14] & q3.z, rw[15] & q3.w,
            rw[16] & q4.x, rw[17] & q4.y, rw[18] & q4.z, rw[19] & q4.w };
        int cnt = 0;
        #pragma unroll
        for (int j = 0; j < NW; ++j) cnt += __popc(cw[j]);
        float xs = 0.f;
        #pragma unroll
        for (int j = 0; j < NW; ++j) {
            unsigned c = cw[j];
            while (c) {
                int b = __ffs(c) - 1; c &= c - 1;
                int pos = pre[j] + __popc(rw[j] & ((1u << b) - 1));
                xs += xr[pos][lane];              // common-neighbor xa from LDS
            }
        }
        float h = xr[p][lane] + xs + k0 + (float)cnt * k1;
        hacc += fmaxf(h, 0.f);                    // ReLU then accumulate
    }
    p1[wave][lane] = hacc;
    __syncthreads();

    // tail: h = relu(xc_v + hsum@Wf + deg*bf + b0a); out = h@W0b + b0b
    float hs = 0.f;
    #pragma unroll
    for (int w = 0; w < 8; ++w) hs += p1[w][lane];      // every wave: full hsum
    float s = 0.f;
    #pragma unroll
    for (int i = 0; i < 8; ++i) {
        const int d = wave * 8 + i;
        s += __shfl(hs, d, 64) * Wf[d * H + lane];
    }
    p2[wave][lane] = s;
    __syncthreads();

    float s2 = 0.f;
    #pragma unroll
    for (int w = 0; w < 8; ++w) s2 += p2[w][lane];
    const float hh = fmaxf(xc[v * H + lane] + (float)deg * bf[lane]
                           + b0a[lane] + s2, 0.f);      // full h, every wave
    float o = 0.f;
    #pragma unroll
    for (int i = 0; i < 8; ++i) {
        const int d = wave * 8 + i;
        o += __shfl(hh, d, 64) * W0b[d * H + lane];
    }
    p1[wave][lane] = o;
    __syncthreads();
    if (wave == 0) {
        float oo = b0b[lane];
        #pragma unroll
        for (int w = 0; w < 8; ++w) oo += p1[w][lane];
        out[v * H + lane] = oo;
    }
}

extern "C" void kernel_launch(void* const* d_in, const int* in_sizes, int n_in,
                              void* d_out, int out_size, void* d_ws, size_t ws_size,
                              hipStream_t stream) {
    const float* x   = (const float*)d_in[0];
    const float* W1a = (const float*)d_in[1];
    const float* b1a = (const float*)d_in[2];
    const float* W1b = (const float*)d_in[3];
    const float* b1b = (const float*)d_in[4];
    const float* W0a = (const float*)d_in[5];
    const float* b0a = (const float*)d_in[6];
    const float* W0b = (const float*)d_in[7];
    const float* b0b = (const float*)d_in[8];
    const int*   ei  = (const int*)d_in[9];
    const int    E   = in_sizes[9] / 2;

    char* ws = (char*)d_ws;
    unsigned* bits = (unsigned*)(ws);                         // 640*24*4 = 61440 B
    float*    xa   = (float*)(ws + 61440);                    // 163840 B
    float*    xc   = (float*)(ws + 61440 + 163840);           // 163840 B
    float*    Wf   = (float*)(ws + 61440 + 2 * 163840);       // 16384 B
    float*    bf   = (float*)(ws + 61440 + 2 * 163840 + 16384);

    hipMemsetAsync(bits, 0, 61440, stream);                   // zero bitmask each launch
    prep<<<329, 512, 0, stream>>>(ei, E, x, W1a, W0a, W1b, b1b, bits, xa, xc, Wf, bf);
    fused<<<NN, 512, 0, stream>>>(xa, xc, W1a, b1a, Wf, bf, b0a, W0b, b0b,
                                  bits, (float*)d_out);
}

// Round 11
// 22.263 us; speedup vs baseline: 1.1100x; 1.1100x over previous
//
#include <hip/hip_runtime.h>

#define NN   640
#define NW   20    // used bitmask words per node
#define NWP  24    // padded row stride (96 B -> every row 16B-aligned)
#define H    64
#define MAXD 96    // degree cap; deg ~ Binomial(1279,.0187), mean 23.9

// ---------------- K1: prep (2-node graph: no memset) ----------------
// blocks 0..319 : waves 0-3: xa = x@W1a, xc = x@W0a for nodes {2b, 2b+1};
//                 waves 4-7: int4-vectorized edge scan -> LDS bitmask for the
//                 block's 2 nodes (zeroed in-block; no global zeroing needed).
// blocks 320..327: Wf = W1b @ W0a (8 rows/block, one row per wave)
// block  328     : bf = b1b @ W0a
__global__ __launch_bounds__(512) void prep(
    const int* __restrict__ ei, int E,
    const float* __restrict__ x,
    const float* __restrict__ W1a, const float* __restrict__ W0a,
    const float* __restrict__ W1b, const float* __restrict__ b1b,
    unsigned* __restrict__ bits, float* __restrict__ xa, float* __restrict__ xc,
    float* __restrict__ Wf, float* __restrict__ bf)
{
    const int t = threadIdx.x, lane = t & 63, wave = t >> 6, bid = blockIdx.x;

    if (bid < 320) {
        __shared__ unsigned sb[2 * NW];
        if (t < 2 * NW) sb[t] = 0u;
        __syncthreads();

        if (wave >= 4) {                      // waves 4-7: vectorized edge scan
            const int st = t - 256;           // 0..255
            const int quads = E >> 2;
            for (int k = st; k < quads; k += 256) {
                const int4 a4 = ((const int4*)ei)[k];
                const int4 b4 = ((const int4*)(ei + E))[k];
                if ((a4.x >> 1) == bid && a4.x != b4.x)
                    atomicOr(&sb[(a4.x & 1) * NW + (b4.x >> 5)], 1u << (b4.x & 31));
                if ((a4.y >> 1) == bid && a4.y != b4.y)
                    atomicOr(&sb[(a4.y & 1) * NW + (b4.y >> 5)], 1u << (b4.y & 31));
                if ((a4.z >> 1) == bid && a4.z != b4.z)
                    atomicOr(&sb[(a4.z & 1) * NW + (b4.z >> 5)], 1u << (b4.z & 31));
                if ((a4.w >> 1) == bid && a4.w != b4.w)
                    atomicOr(&sb[(a4.w & 1) * NW + (b4.w >> 5)], 1u << (b4.w & 31));
            }
            for (int k = (quads << 2) + st; k < E; k += 256) {
                const int a = ei[k], b = ei[k + E];
                if ((a >> 1) == bid && a != b)
                    atomicOr(&sb[(a & 1) * NW + (b >> 5)], 1u << (b & 31));
            }
        } else {                              // waves 0,1: xa; waves 2,3: xc
            const int v = bid * 2 + (wave & 1);
            const float* W = (wave < 2) ? W1a : W0a;
            const float xv = x[v * H + lane];
            float a0 = 0, a1 = 0, a2 = 0, a3 = 0;
            #pragma unroll
            for (int k = 0; k < H; k += 4) {
                a0 += __shfl(xv, k, 64)     * W[k * H + lane];
                a1 += __shfl(xv, k + 1, 64) * W[(k + 1) * H + lane];
                a2 += __shfl(xv, k + 2, 64) * W[(k + 2) * H + lane];
                a3 += __shfl(xv, k + 3, 64) * W[(k + 3) * H + lane];
            }
            float r = (a0 + a1) + (a2 + a3);
            if (wave < 2) xa[v * H + lane] = r; else xc[v * H + lane] = r;
        }
        __syncthreads();
        if (t < 2 * NW) bits[(bid * 2 + t / NW) * NWP + (t % NW)] = sb[t];
    } else if (bid < 328) {
        const int d = (bid - 320) * 8 + wave;
        const float wv = W1b[d * 65 + lane];          // lane e holds W1b[d][e]
        float a0 = 0, a1 = 0, a2 = 0, a3 = 0;
        #pragma unroll
        for (int e = 0; e < 64; e += 4) {
            a0 += __shfl(wv, e, 64)     * W0a[e * H + lane];
            a1 += __shfl(wv, e + 1, 64) * W0a[(e + 1) * H + lane];
            a2 += __shfl(wv, e + 2, 64) * W0a[(e + 2) * H + lane];
            a3 += __shfl(wv, e + 3, 64) * W0a[(e + 3) * H + lane];
        }
        Wf[d * H + lane] = (a0 + a1) + (a2 + a3) + W1b[d * 65 + 64] * W0a[64 * H + lane];
    } else if (wave == 0) {
        const float bv = b1b[lane];
        float a0 = 0, a1 = 0, a2 = 0, a3 = 0;
        #pragma unroll
        for (int e = 0; e < 64; e += 4) {
            a0 += __shfl(bv, e, 64)     * W0a[e * H + lane];
            a1 += __shfl(bv, e + 1, 64) * W0a[(e + 1) * H + lane];
            a2 += __shfl(bv, e + 2, 64) * W0a[(e + 2) * H + lane];
            a3 += __shfl(bv, e + 3, 64) * W0a[(e + 3) * H + lane];
        }
        bf[lane] = (a0 + a1) + (a2 + a3) + b1b[64] * W0a[64 * H + lane];
    }
}

// ---------------- K2: fused per-node ego computation (round-9 verbatim) ----------------
__global__ __launch_bounds__(512, 6) void fused(
    const float* __restrict__ xa,  const float* __restrict__ xc,
    const float* __restrict__ W1a, const float* __restrict__ b1a,
    const float* __restrict__ Wf,  const float* __restrict__ bf,
    const float* __restrict__ b0a,
    const float* __restrict__ W0b, const float* __restrict__ b0b,
    const unsigned* __restrict__ bits,
    float* __restrict__ out)
{
    __shared__ __align__(16) unsigned rowv[NW];
    __shared__ float xr[MAXD][H];                 // xa rows of N(v)
    __shared__ float p1[8][H];
    __shared__ float p2[8][H];
    __shared__ unsigned short ulist[MAXD];
    __shared__ int pre[NW];
    __shared__ int s_deg;

    const int v = blockIdx.x, t = threadIdx.x;
    const int lane = t & 63, wave = t >> 6;

    if (t < NW) rowv[t] = bits[v * NWP + t];
    __syncthreads();

    // enumeration: shfl-scan prefix popcount over the 20 words
    if (wave == 0) {
        unsigned word = (lane < NW) ? rowv[lane] : 0u;
        int pc = __popc(word), scan = pc;
        #pragma unroll
        for (int off = 1; off < 32; off <<= 1) {
            int nb = __shfl_up(scan, off, 64);
            if (lane >= off) scan += nb;
        }
        int o = scan - pc;                        // exclusive prefix
        if (lane < NW) pre[lane] = o;
        unsigned c = word;
        while (c) {
            int b = __ffs(c) - 1; c &= c - 1;
            if (o < MAXD) ulist[o] = (unsigned short)(lane * 32 + b);
            ++o;
        }
        if (lane == NW - 1) s_deg = (o < MAXD) ? o : MAXD;
    }
    __syncthreads();
    const int deg = s_deg;

    // stage xa rows of N(v) into LDS (one coalesced latency round)
    for (int p = wave; p < deg; p += 8)
        xr[p][lane] = xa[ulist[p] * H + lane];

    const float r64 = W1a[64 * H + lane];
    const float k0  = b1a[lane] + r64;            // b1a + 1*W1a[64]
    const float k1  = r64 + W1a[65 * H + lane];   // per-cnt term

    unsigned rw[NW];
    #pragma unroll
    for (int j = 0; j < NW; ++j) rw[j] = rowv[j];
    __syncthreads();

    float hacc = 0.f;
    for (int p = wave; p < deg; p += 8) {
        const uint4* bu = (const uint4*)(bits + ulist[p] * NWP);  // 16B-aligned
        const uint4 q0 = bu[0], q1 = bu[1], q2 = bu[2], q3 = bu[3], q4 = bu[4];
        unsigned cw[NW] = {
            rw[0]  & q0.x, rw[1]  & q0.y, rw[2]  & q0.z, rw[3]  & q0.w,
            rw[4]  & q1.x, rw[5]  & q1.y, rw[6]  & q1.z, rw[7]  & q1.w,
            rw[8]  & q2.x, rw[9]  & q2.y, rw[10] & q2.z, rw[11] & q2.w,
            rw[12] & q3.x, rw[13] & q3.y, rw[14] & q3.z, rw[15] & q3.w,
            rw[16] & q4.x, rw[17] & q4.y, rw[18] & q4.z, rw[19] & q4.w };
        int cnt = 0;
        #pragma unroll
        for (int j = 0; j < NW; ++j) cnt += __popc(cw[j]);
        float xs = 0.f;
        #pragma unroll
        for (int j = 0; j < NW; ++j) {
            unsigned c = cw[j];
            while (c) {
                int b = __ffs(c) - 1; c &= c - 1;
                int pos = pre[j] + __popc(rw[j] & ((1u << b) - 1));
                xs += xr[pos][lane];              // common-neighbor xa from LDS
            }
        }
        float h = xr[p][lane] + xs + k0 + (float)cnt * k1;
        hacc += fmaxf(h, 0.f);                    // ReLU then accumulate
    }
    p1[wave][lane] = hacc;
    __syncthreads();

    // tail: h = relu(xc_v + hsum@Wf + deg*bf + b0a); out = h@W0b + b0b
    float hs = 0.f;
    #pragma unroll
    for (int w = 0; w < 8; ++w) hs += p1[w][lane];      // every wave: full hsum
    float s = 0.f;
    #pragma unroll
    for (int i = 0; i < 8; ++i) {
        const int d = wave * 8 + i;
        s += __shfl(hs, d, 64) * Wf[d * H + lane];
    }
    p2[wave][lane] = s;
    __syncthreads();

    float s2 = 0.f;
    #pragma unroll
    for (int w = 0; w < 8; ++w) s2 += p2[w][lane];
    const float hh = fmaxf(xc[v * H + lane] + (float)deg * bf[lane]
                           + b0a[lane] + s2, 0.f);      // full h, every wave
    float o = 0.f;
    #pragma unroll
    for (int i = 0; i < 8; ++i) {
        const int d = wave * 8 + i;
        o += __shfl(hh, d, 64) * W0b[d * H + lane];
    }
    p1[wave][lane] = o;
    __syncthreads();
    if (wave == 0) {
        float oo = b0b[lane];
        #pragma unroll
        for (int w = 0; w < 8; ++w) oo += p1[w][lane];
        out[v * H + lane] = oo;
    }
}

extern "C" void kernel_launch(void* const* d_in, const int* in_sizes, int n_in,
                              void* d_out, int out_size, void* d_ws, size_t ws_size,
                              hipStream_t stream) {
    const float* x   = (const float*)d_in[0];
    const float* W1a = (const float*)d_in[1];
    const float* b1a = (const float*)d_in[2];
    const float* W1b = (const float*)d_in[3];
    const float* b1b = (const float*)d_in[4];
    const float* W0a = (const float*)d_in[5];
    const float* b0a = (const float*)d_in[6];
    const float* W0b = (const float*)d_in[7];
    const float* b0b = (const float*)d_in[8];
    const int*   ei  = (const int*)d_in[9];
    const int    E   = in_sizes[9] / 2;

    char* ws = (char*)d_ws;
    unsigned* bits = (unsigned*)(ws);                         // 640*24*4 = 61440 B
    float*    xa   = (float*)(ws + 61440);                    // 163840 B
    float*    xc   = (float*)(ws + 61440 + 163840);           // 163840 B
    float*    Wf   = (float*)(ws + 61440 + 2 * 163840);       // 16384 B
    float*    bf   = (float*)(ws + 61440 + 2 * 163840 + 16384);

    prep<<<329, 512, 0, stream>>>(ei, E, x, W1a, W0a, W1b, b1b, bits, xa, xc, Wf, bf);
    fused<<<NN, 512, 0, stream>>>(xa, xc, W1a, b1a, Wf, bf, b0a, W0b, b0b,
                                  bits, (float*)d_out);
}